// Round 1
// baseline (1906.124 us; speedup 1.0000x reference)
//
#include <hip/hip_runtime.h>
#include <math.h>

// Problem constants (B=2, N=768, C_TOKEN=768, C_S=384, C_PAIR=128, H=16, D=48)
namespace {
constexpr int kNB = 2, kN = 768, kCT = 768, kCS = 384, kCP = 128, kNH = 16, kHD = 48;
constexpr float kEps = 1e-5f;
constexpr float kQScale = 0.14433756729740643f;  // 1/sqrt(48)
}

__device__ __forceinline__ float sigf(float x) { return 1.f / (1.f + expf(-x)); }

// ---------------- pack: build [384x1536] adaLN weights, [768x3072] QKVG weights, biases ----
__global__ __launch_bounds__(256) void pack_kernel(
    const float* __restrict__ Wg, const float* __restrict__ Wb,
    const float* __restrict__ bg, const float* __restrict__ bq,
    const float* __restrict__ Wq, const float* __restrict__ Wk,
    const float* __restrict__ Wv, const float* __restrict__ Wgate,
    float* __restrict__ p_ada, float* __restrict__ p_qkvg,
    float* __restrict__ pb_ada, float* __restrict__ pb_qkvg) {
  const int T1 = kCS * 2 * kCT;        // 384*1536
  const int T2 = T1 + kCT * 4 * kCT;   // + 768*3072
  const int T3 = T2 + 2 * kCT;
  const int T4 = T3 + 4 * kCT;
  int idx = blockIdx.x * 256 + threadIdx.x;
  if (idx < T1) {
    int r = idx / (2 * kCT), c = idx % (2 * kCT);
    p_ada[idx] = (c < kCT) ? Wg[r * kCT + c] : Wb[r * kCT + (c - kCT)];
  } else if (idx < T2) {
    int k = idx - T1;
    int r = k / (4 * kCT), c = k % (4 * kCT);
    int sel = c / kCT, cc = c % kCT;
    const float* w = sel == 0 ? Wq : sel == 1 ? Wk : sel == 2 ? Wv : Wgate;
    p_qkvg[k] = w[r * kCT + cc];
  } else if (idx < T3) {
    int c = idx - T2;
    pb_ada[c] = (c < kCT) ? bg[c] : 0.f;
  } else if (idx < T4) {
    int c = idx - T3;
    pb_qkvg[c] = (c < kCT) ? bq[c] : 0.f;
  }
}

// ---------------- LayerNorm over last dim (no affine) -------------------------------------
__global__ __launch_bounds__(256) void ln_kernel(const float* __restrict__ x,
                                                 float* __restrict__ y, int C) {
  const int row = blockIdx.x;
  const float* xr = x + (size_t)row * C;
  float vals[3];
  int cnt = 0;
  float s = 0.f, ss = 0.f;
  for (int c = threadIdx.x; c < C; c += 256) {
    float v = xr[c];
    vals[cnt++] = v;
    s += v;
    ss = fmaf(v, v, ss);
  }
#pragma unroll
  for (int m = 1; m < 64; m <<= 1) { s += __shfl_xor(s, m); ss += __shfl_xor(ss, m); }
  __shared__ float red[8];
  __shared__ float mb[2];
  const int wid = threadIdx.x >> 6, lane = threadIdx.x & 63;
  if (lane == 0) { red[wid * 2] = s; red[wid * 2 + 1] = ss; }
  __syncthreads();
  if (threadIdx.x == 0) {
    float S = red[0] + red[2] + red[4] + red[6];
    float SS = red[1] + red[3] + red[5] + red[7];
    float mean = S / C;
    float var = SS / C - mean * mean;
    mb[0] = mean;
    mb[1] = rsqrtf(var + kEps);
  }
  __syncthreads();
  const float mean = mb[0], rs = mb[1];
  cnt = 0;
  for (int c = threadIdx.x; c < C; c += 256) y[(size_t)row * C + c] = (vals[cnt++] - mean) * rs;
}

// ---------------- a_norm = sigmoid(G)*a_ln + Bv  (G|Bv packed in gb [1536x1536]) ----------
__global__ __launch_bounds__(256) void anorm_kernel(const float* __restrict__ gb,
                                                    const float* __restrict__ a_ln,
                                                    float* __restrict__ a_norm) {
  int idx = blockIdx.x * 256 + threadIdx.x;  // < 1536*768
  int row = idx / kCT, col = idx % kCT;
  float g = gb[(size_t)row * (2 * kCT) + col];
  float bv = gb[(size_t)row * (2 * kCT) + kCT + col];
  a_norm[idx] = sigf(g) * a_ln[idx] + bv;
}

// ---------------- generic fp32 GEMM: C[M,N] = A[M,K] @ W[K,N]  (dims all % 64/16 == 0) ----
// epilogue: +bias[col] (if bias), sigmoid for col>=sig_start, *= aux[row,col] (if aux)
__global__ __launch_bounds__(256) void gemm_kernel(
    const float* __restrict__ A, const float* __restrict__ W,
    const float* __restrict__ bias, const float* __restrict__ aux,
    float* __restrict__ C, int M, int Nn, int K, int sig_start) {
  __shared__ float As[16][64];
  __shared__ float Ws[16][64];
  const int t = threadIdx.x;
  const int bm = blockIdx.y * 64, bn = blockIdx.x * 64;
  const int tm = (t >> 4) * 4, tn = (t & 15) * 4;
  const int la_m = t >> 2, la_k = (t & 3) * 4;   // A tile: 64 m x 16 k
  const int lw_k = t >> 4, lw_n = (t & 15) * 4;  // W tile: 16 k x 64 n
  float acc[4][4] = {};
  for (int k0 = 0; k0 < K; k0 += 16) {
    float4 a4 = *(const float4*)&A[(size_t)(bm + la_m) * K + k0 + la_k];
    float4 w4 = *(const float4*)&W[(size_t)(k0 + lw_k) * Nn + bn + lw_n];
    __syncthreads();
    As[la_k + 0][la_m] = a4.x;
    As[la_k + 1][la_m] = a4.y;
    As[la_k + 2][la_m] = a4.z;
    As[la_k + 3][la_m] = a4.w;
    *(float4*)&Ws[lw_k][lw_n] = w4;
    __syncthreads();
#pragma unroll
    for (int k = 0; k < 16; ++k) {
      float4 av = *(const float4*)&As[k][tm];
      float4 wv = *(const float4*)&Ws[k][tn];
      float a_[4] = {av.x, av.y, av.z, av.w};
      float w_[4] = {wv.x, wv.y, wv.z, wv.w};
#pragma unroll
      for (int ii = 0; ii < 4; ++ii)
#pragma unroll
        for (int jj = 0; jj < 4; ++jj) acc[ii][jj] = fmaf(a_[ii], w_[jj], acc[ii][jj]);
    }
  }
#pragma unroll
  for (int ii = 0; ii < 4; ++ii)
#pragma unroll
    for (int jj = 0; jj < 4; ++jj) {
      int row = bm + tm + ii, col = bn + tn + jj;
      float v = acc[ii][jj];
      if (bias) v += bias[col];
      if (col >= sig_start) v = sigf(v);
      if (aux) v *= aux[(size_t)row * Nn + col];
      C[(size_t)row * Nn + col] = v;
    }
}

// ---------------- pair bias: pb[b,h,i,j] = LN(z[b,i,j,:])*gamma+beta @ Wpb + mask ---------
// wave layout: lane = cg*4+hg; cg (16) covers 8 channels, hg (4) covers 4 heads.
// Wpb slice lives in registers (32/lane); stats & acc reduced over cg via xor 4,8,16,32.
__global__ __launch_bounds__(256) void pairbias_kernel(
    const float* __restrict__ z, const float* __restrict__ mask,
    const float* __restrict__ Wpb, const float* __restrict__ gamma,
    const float* __restrict__ beta, float* __restrict__ pb) {
  const int i = blockIdx.x, b = blockIdx.y;
  const int t = threadIdx.x, wid = t >> 6, lane = t & 63;
  const int cg = lane >> 2;  // 0..15 -> c = cg*8 .. cg*8+7
  const int hg = lane & 3;   // 0..3  -> h = hg*4 .. hg*4+3
  float wr[8][4], gam[8], bet[8];
#pragma unroll
  for (int cc = 0; cc < 8; ++cc) {
    int c = cg * 8 + cc;
    gam[cc] = gamma[c];
    bet[cc] = beta[c];
#pragma unroll
    for (int hh = 0; hh < 4; ++hh) wr[cc][hh] = Wpb[c * kNH + hg * 4 + hh];
  }
  const size_t zrow = (size_t)(b * kN + i) * kN;
  const size_t mrow = (size_t)(b * kN + i) * kN;
  for (int j = wid * 192; j < wid * 192 + 192; ++j) {
    const float4 za = *(const float4*)&z[(zrow + j) * kCP + cg * 8];
    const float4 zb = *(const float4*)&z[(zrow + j) * kCP + cg * 8 + 4];
    float zv[8] = {za.x, za.y, za.z, za.w, zb.x, zb.y, zb.z, zb.w};
    float s = 0.f, ss = 0.f;
#pragma unroll
    for (int cc = 0; cc < 8; ++cc) { s += zv[cc]; ss = fmaf(zv[cc], zv[cc], ss); }
#pragma unroll
    for (int m = 4; m < 64; m <<= 1) { s += __shfl_xor(s, m); ss += __shfl_xor(ss, m); }
    const float mean = s * (1.f / 128.f);
    const float var = ss * (1.f / 128.f) - mean * mean;
    const float rs = rsqrtf(var + kEps);
    float acc[4] = {0.f, 0.f, 0.f, 0.f};
#pragma unroll
    for (int cc = 0; cc < 8; ++cc) {
      float zn = fmaf((zv[cc] - mean) * rs, gam[cc], bet[cc]);
#pragma unroll
      for (int hh = 0; hh < 4; ++hh) acc[hh] = fmaf(zn, wr[cc][hh], acc[hh]);
    }
#pragma unroll
    for (int m = 4; m < 64; m <<= 1) {
#pragma unroll
      for (int hh = 0; hh < 4; ++hh) acc[hh] += __shfl_xor(acc[hh], m);
    }
    if (cg == 0) {
      const float bm = mask[mrow + j];
#pragma unroll
      for (int hh = 0; hh < 4; ++hh)
        pb[(((size_t)(b * kNH + hg * 4 + hh)) * kN + i) * kN + j] = acc[hh] + bm;
    }
  }
}

// ---------------- attention: per-wave (b,h,i); 4 waves/block share k/v LDS tiles ----------
// qkvg layout: row (b*768+n) x 3072 cols: [q | k | v | sigmoid(gate)], col within = h*48+d
__global__ __launch_bounds__(256) void attn_kernel(
    const float* __restrict__ qkvg, const float* __restrict__ pb,
    float* __restrict__ o_out) {
  __shared__ float kt[64 * 52];  // row padded 48->52: b128 reads stride 13 quads (odd) -> 2-way max
  __shared__ float vt[64 * 52];
  __shared__ float qs[4][48];
  const int b = blockIdx.z, h = blockIdx.y;
  const int t = threadIdx.x, wid = t >> 6, lane = t & 63;
  const int i = blockIdx.x * 4 + wid;
  const size_t rowi = (size_t)(b * kN + i) * (4 * kCT);
  if (lane < 12) {
    float4 q4 = *(const float4*)&qkvg[rowi + h * kHD + lane * 4];
    qs[wid][lane * 4 + 0] = q4.x * kQScale;
    qs[wid][lane * 4 + 1] = q4.y * kQScale;
    qs[wid][lane * 4 + 2] = q4.z * kQScale;
    qs[wid][lane * 4 + 3] = q4.w * kQScale;
  }
  float o[48];
#pragma unroll
  for (int d = 0; d < 48; ++d) o[d] = 0.f;
  float mrun = -INFINITY, lsum = 0.f;
  const float* pbrow = &pb[((size_t)(b * kNH + h) * kN + i) * kN];
  for (int c = 0; c < 12; ++c) {
    __syncthreads();
#pragma unroll
    for (int r = 0; r < 3; ++r) {
      int f = t + r * 256;          // 768 float4 per tile
      int jl = f / 12, d4 = f % 12;
      size_t rowj = (size_t)(b * kN + c * 64 + jl) * (4 * kCT);
      *(float4*)&kt[jl * 52 + d4 * 4] = *(const float4*)&qkvg[rowj + kCT + h * kHD + d4 * 4];
      *(float4*)&vt[jl * 52 + d4 * 4] = *(const float4*)&qkvg[rowj + 2 * kCT + h * kHD + d4 * 4];
    }
    __syncthreads();
    float logit = pbrow[c * 64 + lane];
#pragma unroll
    for (int d4 = 0; d4 < 12; ++d4) {
      float4 kk = *(const float4*)&kt[lane * 52 + d4 * 4];
      float4 qq = *(const float4*)&qs[wid][d4 * 4];
      logit = fmaf(qq.x, kk.x, logit);
      logit = fmaf(qq.y, kk.y, logit);
      logit = fmaf(qq.z, kk.z, logit);
      logit = fmaf(qq.w, kk.w, logit);
    }
    float mx = logit;
#pragma unroll
    for (int m = 1; m < 64; m <<= 1) mx = fmaxf(mx, __shfl_xor(mx, m));
    const float mnew = fmaxf(mrun, mx);
    const float alpha = expf(mrun - mnew);  // first iter: exp(-inf)=0
    const float p = expf(logit - mnew);
    lsum = fmaf(lsum, alpha, p);
#pragma unroll
    for (int d4 = 0; d4 < 12; ++d4) {
      float4 vv = *(const float4*)&vt[lane * 52 + d4 * 4];
      o[d4 * 4 + 0] = fmaf(o[d4 * 4 + 0], alpha, p * vv.x);
      o[d4 * 4 + 1] = fmaf(o[d4 * 4 + 1], alpha, p * vv.y);
      o[d4 * 4 + 2] = fmaf(o[d4 * 4 + 2], alpha, p * vv.z);
      o[d4 * 4 + 3] = fmaf(o[d4 * 4 + 3], alpha, p * vv.w);
    }
    mrun = mnew;
  }
#pragma unroll
  for (int m = 1; m < 64; m <<= 1) lsum += __shfl_xor(lsum, m);
#pragma unroll
  for (int d = 0; d < 48; ++d) {
#pragma unroll
    for (int m = 1; m < 64; m <<= 1) o[d] += __shfl_xor(o[d], m);
  }
  if (lane == 0) {
    const float inv = 1.f / lsum;
#pragma unroll
    for (int d4 = 0; d4 < 12; ++d4) {
      float4 g4 = *(const float4*)&qkvg[rowi + 3 * kCT + h * kHD + d4 * 4];
      float4 r;
      r.x = g4.x * o[d4 * 4 + 0] * inv;
      r.y = g4.y * o[d4 * 4 + 1] * inv;
      r.z = g4.z * o[d4 * 4 + 2] * inv;
      r.w = g4.w * o[d4 * 4 + 3] * inv;
      *(float4*)&o_out[(size_t)(b * kN + i) * kCT + h * kHD + d4 * 4] = r;
    }
  }
}

// ==========================================================================================
extern "C" void kernel_launch(void* const* d_in, const int* in_sizes, int n_in,
                              void* d_out, int out_size, void* d_ws, size_t ws_size,
                              hipStream_t stream) {
  const float* a      = (const float*)d_in[0];
  const float* s      = (const float*)d_in[1];
  const float* z      = (const float*)d_in[2];
  const float* mask   = (const float*)d_in[3];
  const float* Wg_ada = (const float*)d_in[4];
  const float* bg_ada = (const float*)d_in[5];
  const float* Wb_ada = (const float*)d_in[6];
  const float* Wq     = (const float*)d_in[7];
  const float* bq     = (const float*)d_in[8];
  const float* Wk     = (const float*)d_in[9];
  const float* Wv     = (const float*)d_in[10];
  const float* Wpb    = (const float*)d_in[11];
  const float* pn_g   = (const float*)d_in[12];
  const float* pn_b   = (const float*)d_in[13];
  const float* Wgate  = (const float*)d_in[14];
  const float* Wout   = (const float*)d_in[15];
  const float* Wog    = (const float*)d_in[16];
  const float* bog    = (const float*)d_in[17];
  float* out = (float*)d_out;

  // workspace carve-up (total ~34.2M floats = 137 MB)
  float* w = (float*)d_ws;
  float* a_ln   = w; w += 1536 * 768;
  float* s_ln   = w; w += 1536 * 384;
  float* gb     = w; w += 1536 * 1536;
  float* a_nrm  = w; w += 1536 * 768;
  float* qkvg   = w; w += (size_t)1536 * 3072;
  float* ogate  = w; w += 1536 * 768;
  float* pbias  = w; w += (size_t)2 * 16 * 768 * 768;
  float* o_g    = w; w += 1536 * 768;
  float* p_ada  = w; w += 384 * 1536;
  float* p_qkvg = w; w += (size_t)768 * 3072;
  float* pb_ada = w; w += 1536;
  float* pb_qk  = w; w += 3072;

  const int packTot = 384 * 1536 + 768 * 3072 + 1536 + 3072;
  pack_kernel<<<dim3((packTot + 255) / 256), 256, 0, stream>>>(
      Wg_ada, Wb_ada, bg_ada, bq, Wq, Wk, Wv, Wgate, p_ada, p_qkvg, pb_ada, pb_qk);
  ln_kernel<<<dim3(1536), 256, 0, stream>>>(a, a_ln, 768);
  ln_kernel<<<dim3(1536), 256, 0, stream>>>(s, s_ln, 384);
  // gb = [ s_ln@Wg_ada + bg | s_ln@Wb_ada ]
  gemm_kernel<<<dim3(1536 / 64, 1536 / 64), 256, 0, stream>>>(
      s_ln, p_ada, pb_ada, nullptr, gb, 1536, 1536, 384, 1 << 30);
  anorm_kernel<<<dim3(1536 * 768 / 256), 256, 0, stream>>>(gb, a_ln, a_nrm);
  // qkvg = a_norm @ [Wq|Wk|Wv|Wgate] (+bq on q, sigmoid on gate cols >= 2304)
  gemm_kernel<<<dim3(3072 / 64, 1536 / 64), 256, 0, stream>>>(
      a_nrm, p_qkvg, pb_qk, nullptr, qkvg, 1536, 3072, 768, 2304);
  // ogate = sigmoid(s @ Wog + bog)
  gemm_kernel<<<dim3(768 / 64, 1536 / 64), 256, 0, stream>>>(
      s, Wog, bog, nullptr, ogate, 1536, 768, 384, 0);
  pairbias_kernel<<<dim3(768, 2), 256, 0, stream>>>(z, mask, Wpb, pn_g, pn_b, pbias);
  attn_kernel<<<dim3(192, 16, 2), 256, 0, stream>>>(qkvg, pbias, o_g);
  // out = ogate * (o_g @ Wout)
  gemm_kernel<<<dim3(768 / 64, 1536 / 64), 256, 0, stream>>>(
      o_g, Wout, nullptr, ogate, out, 1536, 768, 768, 1 << 30);
}

// Round 2
// 1457.443 us; speedup vs baseline: 1.3079x; 1.3079x over previous
//
#include <hip/hip_runtime.h>
#include <math.h>
#include <stdint.h>

namespace {
constexpr int kN = 768, kCT = 768, kCS = 384, kCP = 128, kNH = 16, kHD = 48;
constexpr float kEps = 1e-5f;
constexpr float kQScale = 0.14433756729740643f;  // 1/sqrt(48)
}

typedef __attribute__((ext_vector_type(8))) short short8;
typedef __attribute__((ext_vector_type(4))) float floatx4;

__device__ __forceinline__ float sigf(float x) { return 1.f / (1.f + expf(-x)); }
__device__ __forceinline__ unsigned short f2bf(float x) {  // RNE bf16 round
  uint32_t v = __builtin_bit_cast(uint32_t, x);
  return (unsigned short)((v + 0x7fffu + ((v >> 16) & 1u)) >> 16);
}
__device__ __forceinline__ float bf2f(unsigned short u) {
  uint32_t v = ((uint32_t)u) << 16;
  return __builtin_bit_cast(float, v);
}

#if __has_builtin(__builtin_amdgcn_global_load_lds)
#define HAVE_GLL 1
#define ASYNC_COPY16(gp, lp)                                                     \
  __builtin_amdgcn_global_load_lds((const __attribute__((address_space(1))) void*)(gp), \
                                   (__attribute__((address_space(3))) void*)(lp), 16, 0, 0)
#else
#define HAVE_GLL 0
#endif

// ---------------- pack: bf16-transposed weights, fused biases, pairbias precompute --------
__global__ __launch_bounds__(256) void pack_kernel(
    const float* __restrict__ Wg, const float* __restrict__ Wb,
    const float* __restrict__ bg, const float* __restrict__ bq,
    const float* __restrict__ Wq, const float* __restrict__ Wk,
    const float* __restrict__ Wv, const float* __restrict__ Wgate,
    const float* __restrict__ Wog, const float* __restrict__ Wout,
    const float* __restrict__ s, const float* __restrict__ Wpb,
    const float* __restrict__ gamma, const float* __restrict__ beta,
    unsigned short* __restrict__ p_adaT, unsigned short* __restrict__ p_qkvgT,
    unsigned short* __restrict__ WogT, unsigned short* __restrict__ WoutT,
    float* __restrict__ pb_ada, float* __restrict__ pb_qk,
    unsigned short* __restrict__ s_bf, float* __restrict__ gamW,
    float* __restrict__ pairC) {
  const int T1 = 1536 * 384;
  const int T2 = T1 + 3072 * 768;
  const int T3 = T2 + 768 * 384;
  const int T4 = T3 + 768 * 768;
  const int T5 = T4 + 1536;
  const int T6 = T5 + 3072;
  const int T7 = T6 + 1536 * 384;
  const int T8 = T7 + 2048;
  const int T9 = T8 + 32;
  int idx = blockIdx.x * 256 + threadIdx.x;
  if (idx < T1) {  // adaLN weights ^T: [1536 n][384 k]
    int n = idx / 384, k = idx % 384;
    float w = (n < 768) ? Wg[k * 768 + n] : Wb[k * 768 + (n - 768)];
    p_adaT[idx] = f2bf(w);
  } else if (idx < T2) {  // qkvg ^T: [3072 n][768 k]
    int r = idx - T1;
    int n = r / 768, k = r % 768;
    int sel = n / 768, nn = n - sel * 768;
    const float* w = sel == 0 ? Wq : sel == 1 ? Wk : sel == 2 ? Wv : Wgate;
    p_qkvgT[r] = f2bf(w[k * 768 + nn]);
  } else if (idx < T3) {  // Wog ^T: [768][384]
    int r = idx - T2;
    int n = r / 384, k = r % 384;
    WogT[r] = f2bf(Wog[k * 768 + n]);
  } else if (idx < T4) {  // Wout ^T: [768][768]
    int r = idx - T3;
    int n = r / 768, k = r % 768;
    WoutT[r] = f2bf(Wout[k * 768 + n]);
  } else if (idx < T5) {
    int c = idx - T4;
    pb_ada[c] = (c < 768) ? bg[c] : 0.f;
  } else if (idx < T6) {
    int c = idx - T5;
    pb_qk[c] = (c < 768) ? bq[c] : 0.f;
  } else if (idx < T7) {
    int r = idx - T6;
    s_bf[r] = f2bf(s[r]);
  } else if (idx < T8) {  // gamW[c][h] = gamma[c]*Wpb[c][h]
    int r = idx - T7;
    int c = r >> 4, h = r & 15;
    gamW[r] = gamma[c] * Wpb[c * 16 + h];
  } else if (idx < T9) {  // pairC[0:16]=sum_c beta*Wpb, pairC[16:32]=sum_c gamma*Wpb
    int r = idx - T8;
    float acc = 0.f;
    if (r < 16) {
      for (int c = 0; c < 128; ++c) acc += beta[c] * Wpb[c * 16 + r];
      pairC[r] = acc;
    } else {
      int h = r - 16;
      for (int c = 0; c < 128; ++c) acc += gamma[c] * Wpb[c * 16 + h];
      pairC[r] = acc;
    }
  }
}

// ---------------- LayerNorm over last dim (no affine), fp32 out --------------------------
__global__ __launch_bounds__(256) void ln_kernel(const float* __restrict__ x,
                                                 float* __restrict__ y, int C) {
  const int row = blockIdx.x;
  const float* xr = x + (size_t)row * C;
  float vals[3];
  int cnt = 0;
  float s = 0.f, ss = 0.f;
  for (int c = threadIdx.x; c < C; c += 256) {
    float v = xr[c];
    vals[cnt++] = v;
    s += v;
    ss = fmaf(v, v, ss);
  }
#pragma unroll
  for (int m = 1; m < 64; m <<= 1) { s += __shfl_xor(s, m); ss += __shfl_xor(ss, m); }
  __shared__ float red[8];
  __shared__ float mb[2];
  const int wid = threadIdx.x >> 6, lane = threadIdx.x & 63;
  if (lane == 0) { red[wid * 2] = s; red[wid * 2 + 1] = ss; }
  __syncthreads();
  if (threadIdx.x == 0) {
    float S = red[0] + red[2] + red[4] + red[6];
    float SS = red[1] + red[3] + red[5] + red[7];
    float mean = S / C;
    float var = SS / C - mean * mean;
    mb[0] = mean;
    mb[1] = rsqrtf(var + kEps);
  }
  __syncthreads();
  const float mean = mb[0], rs = mb[1];
  cnt = 0;
  for (int c = threadIdx.x; c < C; c += 256) y[(size_t)row * C + c] = (vals[cnt++] - mean) * rs;
}

// ---------------- LayerNorm, bf16 out ----------------------------------------------------
__global__ __launch_bounds__(256) void ln_bf_kernel(const float* __restrict__ x,
                                                    unsigned short* __restrict__ y, int C) {
  const int row = blockIdx.x;
  const float* xr = x + (size_t)row * C;
  float vals[3];
  int cnt = 0;
  float s = 0.f, ss = 0.f;
  for (int c = threadIdx.x; c < C; c += 256) {
    float v = xr[c];
    vals[cnt++] = v;
    s += v;
    ss = fmaf(v, v, ss);
  }
#pragma unroll
  for (int m = 1; m < 64; m <<= 1) { s += __shfl_xor(s, m); ss += __shfl_xor(ss, m); }
  __shared__ float red[8];
  __shared__ float mb[2];
  const int wid = threadIdx.x >> 6, lane = threadIdx.x & 63;
  if (lane == 0) { red[wid * 2] = s; red[wid * 2 + 1] = ss; }
  __syncthreads();
  if (threadIdx.x == 0) {
    float S = red[0] + red[2] + red[4] + red[6];
    float SS = red[1] + red[3] + red[5] + red[7];
    float mean = S / C;
    float var = SS / C - mean * mean;
    mb[0] = mean;
    mb[1] = rsqrtf(var + kEps);
  }
  __syncthreads();
  const float mean = mb[0], rs = mb[1];
  cnt = 0;
  for (int c = threadIdx.x; c < C; c += 256)
    y[(size_t)row * C + c] = f2bf((vals[cnt++] - mean) * rs);
}

// ---------------- a_norm = sigmoid(G)*a_ln + Bv  -> bf16 ---------------------------------
__global__ __launch_bounds__(256) void anorm_kernel(const float* __restrict__ gb,
                                                    const float* __restrict__ a_ln,
                                                    unsigned short* __restrict__ a_norm) {
  int idx = blockIdx.x * 256 + threadIdx.x;  // < 1536*768
  int row = idx / kCT, col = idx % kCT;
  float g = gb[(size_t)row * (2 * kCT) + col];
  float bv = gb[(size_t)row * (2 * kCT) + kCT + col];
  a_norm[idx] = f2bf(sigf(g) * a_ln[idx] + bv);
}

// ---------------- bf16 MFMA GEMM: C[M,N] = A[M,K] @ Wt[N,K]^T, fp32 out -------------------
// 128x128 tile, BK=32, 4 waves (2x2 of 64x64), 16x16x32 MFMA, XOR-swizzled LDS,
// global_load_lds width 16. Epilogue: +bias[col], sigmoid col>=sig_start, *aux[row,col].
__global__ __launch_bounds__(256) void gemm_bf_kernel(
    const unsigned short* __restrict__ A, const unsigned short* __restrict__ Wt,
    const float* __restrict__ bias, const float* __restrict__ aux,
    float* __restrict__ C, int M, int Nn, int K, int sig_start) {
  __shared__ __align__(16) unsigned short As[128 * 32];
  __shared__ __align__(16) unsigned short Bs[128 * 32];
  const int t = threadIdx.x;
  const int wid = t >> 6, lane = t & 63;
  const int quad = lane >> 4, m16 = lane & 15;
  const int wm = (wid >> 1) * 64, wn = (wid & 1) * 64;
  const int bm = blockIdx.y * 128, bn = blockIdx.x * 128;
  const int swz = quad ^ ((m16 >> 1) & 3);
  // staging: chunk ci holds global (row=ci>>2, kchunk=(ci&3)^((row>>1)&3)) of this k0-slab
  const int ci0 = t, ci1 = t + 256;
  const int am0 = ci0 >> 2, ak0 = ((ci0 & 3) ^ ((am0 >> 1) & 3)) * 8;
  const int am1 = ci1 >> 2, ak1 = ((ci1 & 3) ^ ((am1 >> 1) & 3)) * 8;
  const unsigned short* ga0 = A + (size_t)(bm + am0) * K + ak0;
  const unsigned short* ga1 = A + (size_t)(bm + am1) * K + ak1;
  const unsigned short* gw0 = Wt + (size_t)(bn + am0) * K + ak0;
  const unsigned short* gw1 = Wt + (size_t)(bn + am1) * K + ak1;
  floatx4 acc[4][4] = {};
  for (int k0 = 0; k0 < K; k0 += 32) {
    __syncthreads();
#if HAVE_GLL
    ASYNC_COPY16(ga0 + k0, &As[ci0 * 8]);
    ASYNC_COPY16(ga1 + k0, &As[ci1 * 8]);
    ASYNC_COPY16(gw0 + k0, &Bs[ci0 * 8]);
    ASYNC_COPY16(gw1 + k0, &Bs[ci1 * 8]);
#else
    short8 ra0 = *(const short8*)(ga0 + k0);
    short8 ra1 = *(const short8*)(ga1 + k0);
    short8 rw0 = *(const short8*)(gw0 + k0);
    short8 rw1 = *(const short8*)(gw1 + k0);
    *(short8*)&As[ci0 * 8] = ra0;
    *(short8*)&As[ci1 * 8] = ra1;
    *(short8*)&Bs[ci0 * 8] = rw0;
    *(short8*)&Bs[ci1 * 8] = rw1;
#endif
    __syncthreads();
    short8 af[4], bfv[4];
#pragma unroll
    for (int tm = 0; tm < 4; ++tm)
      af[tm] = *(const short8*)&As[(wm + tm * 16 + m16) * 32 + swz * 8];
#pragma unroll
    for (int tn = 0; tn < 4; ++tn)
      bfv[tn] = *(const short8*)&Bs[(wn + tn * 16 + m16) * 32 + swz * 8];
#pragma unroll
    for (int tm = 0; tm < 4; ++tm)
#pragma unroll
      for (int tn = 0; tn < 4; ++tn)
        acc[tm][tn] = __builtin_amdgcn_mfma_f32_16x16x32_bf16(af[tm], bfv[tn], acc[tm][tn], 0, 0, 0);
  }
  // epilogue: C/D layout col=lane&15, row=quad*4+reg
#pragma unroll
  for (int tm = 0; tm < 4; ++tm) {
    const int row0 = bm + wm + tm * 16 + quad * 4;
#pragma unroll
    for (int tn = 0; tn < 4; ++tn) {
      const int col = bn + wn + tn * 16 + m16;
      const float badd = bias ? bias[col] : 0.f;
#pragma unroll
      for (int r = 0; r < 4; ++r) {
        float v = acc[tm][tn][r] + badd;
        if (col >= sig_start) v = sigf(v);
        if (aux) v *= aux[(size_t)(row0 + r) * Nn + col];
        C[(size_t)(row0 + r) * Nn + col] = v;
      }
    }
  }
}

// ---------------- pair bias v2: thread-per-j, LN folded into weights, bf16 out ------------
// pb[b,h,i,j] = rs*(sum_c z*gamW[c,h] - mean*gwsum[h]) + constB[h] + mask[b,i,j]
__global__ __launch_bounds__(256) void pairbias2_kernel(
    const float* __restrict__ z, const float* __restrict__ mask,
    const float* __restrict__ gamW, const float* __restrict__ pairC,
    unsigned short* __restrict__ pb) {
  __shared__ float4 gw[512];   // gamW as 128 c x 4 float4 (16 h)
  __shared__ float cbs[32];    // [0:16)=constB, [16:32)=gwsum
  const int t = threadIdx.x;
  gw[t] = ((const float4*)gamW)[t];
  gw[t + 256] = ((const float4*)gamW)[t + 256];
  if (t < 32) cbs[t] = pairC[t];
  __syncthreads();
  const int b = blockIdx.z, i = blockIdx.y;
  const int j = blockIdx.x * 256 + t;
  const float4* zr = (const float4*)&z[((size_t)(b * kN + i) * kN + j) * kCP];
  float sum = 0.f, ss = 0.f;
  floatx4 accv[4] = {};
#pragma unroll 2
  for (int ch = 0; ch < 8; ++ch) {  // 16 channels per chunk
    float4 v4[4];
#pragma unroll
    for (int u = 0; u < 4; ++u) v4[u] = zr[ch * 4 + u];
    const float* vv = (const float*)v4;
#pragma unroll
    for (int u = 0; u < 16; ++u) {
      const float v = vv[u];
      sum += v;
      ss = fmaf(v, v, ss);
      const int c = ch * 16 + u;
#pragma unroll
      for (int q = 0; q < 4; ++q) {
        const float4 g = gw[c * 4 + q];
        accv[q][0] = fmaf(v, g.x, accv[q][0]);
        accv[q][1] = fmaf(v, g.y, accv[q][1]);
        accv[q][2] = fmaf(v, g.z, accv[q][2]);
        accv[q][3] = fmaf(v, g.w, accv[q][3]);
      }
    }
  }
  const float mean = sum * (1.f / 128.f);
  const float var = ss * (1.f / 128.f) - mean * mean;
  const float rs = rsqrtf(var + kEps);
  const float mk = mask[(size_t)(b * kN + i) * kN + j];
  const size_t pbase = ((size_t)(b * kNH) * kN + i) * kN + j;
#pragma unroll
  for (int h = 0; h < 16; ++h) {
    const float a = accv[h >> 2][h & 3];
    const float res = fmaf(rs, fmaf(-mean, cbs[16 + h], a), cbs[h]) + mk;
    pb[pbase + (size_t)h * kN * kN] = f2bf(res);  // coalesced: lane=j
  }
}

// ---------------- attention: per-wave (b,h,i); 4 waves/block share k/v LDS tiles ----------
__global__ __launch_bounds__(256) void attn_kernel(
    const float* __restrict__ qkvg, const unsigned short* __restrict__ pb,
    unsigned short* __restrict__ o_out) {
  __shared__ float kt[64 * 52];
  __shared__ float vt[64 * 52];
  __shared__ float qs[4][48];
  const int b = blockIdx.z, h = blockIdx.y;
  const int t = threadIdx.x, wid = t >> 6, lane = t & 63;
  const int i = blockIdx.x * 4 + wid;
  const size_t rowi = (size_t)(b * kN + i) * (4 * kCT);
  if (lane < 12) {
    float4 q4 = *(const float4*)&qkvg[rowi + h * kHD + lane * 4];
    qs[wid][lane * 4 + 0] = q4.x * kQScale;
    qs[wid][lane * 4 + 1] = q4.y * kQScale;
    qs[wid][lane * 4 + 2] = q4.z * kQScale;
    qs[wid][lane * 4 + 3] = q4.w * kQScale;
  }
  float o[48];
#pragma unroll
  for (int d = 0; d < 48; ++d) o[d] = 0.f;
  float mrun = -INFINITY, lsum = 0.f;
  const unsigned short* pbrow = &pb[((size_t)(b * kNH + h) * kN + i) * kN];
  for (int c = 0; c < 12; ++c) {
    __syncthreads();
#pragma unroll
    for (int r = 0; r < 3; ++r) {
      int f = t + r * 256;
      int jl = f / 12, d4 = f % 12;
      size_t rowj = (size_t)(b * kN + c * 64 + jl) * (4 * kCT);
      *(float4*)&kt[jl * 52 + d4 * 4] = *(const float4*)&qkvg[rowj + kCT + h * kHD + d4 * 4];
      *(float4*)&vt[jl * 52 + d4 * 4] = *(const float4*)&qkvg[rowj + 2 * kCT + h * kHD + d4 * 4];
    }
    __syncthreads();
    float logit = bf2f(pbrow[c * 64 + lane]);
#pragma unroll
    for (int d4 = 0; d4 < 12; ++d4) {
      float4 kk = *(const float4*)&kt[lane * 52 + d4 * 4];
      float4 qq = *(const float4*)&qs[wid][d4 * 4];
      logit = fmaf(qq.x, kk.x, logit);
      logit = fmaf(qq.y, kk.y, logit);
      logit = fmaf(qq.z, kk.z, logit);
      logit = fmaf(qq.w, kk.w, logit);
    }
    float mx = logit;
#pragma unroll
    for (int m = 1; m < 64; m <<= 1) mx = fmaxf(mx, __shfl_xor(mx, m));
    const float mnew = fmaxf(mrun, mx);
    const float alpha = expf(mrun - mnew);
    const float p = expf(logit - mnew);
    lsum = fmaf(lsum, alpha, p);
#pragma unroll
    for (int d4 = 0; d4 < 12; ++d4) {
      float4 vv = *(const float4*)&vt[lane * 52 + d4 * 4];
      o[d4 * 4 + 0] = fmaf(o[d4 * 4 + 0], alpha, p * vv.x);
      o[d4 * 4 + 1] = fmaf(o[d4 * 4 + 1], alpha, p * vv.y);
      o[d4 * 4 + 2] = fmaf(o[d4 * 4 + 2], alpha, p * vv.z);
      o[d4 * 4 + 3] = fmaf(o[d4 * 4 + 3], alpha, p * vv.w);
    }
    mrun = mnew;
  }
#pragma unroll
  for (int m = 1; m < 64; m <<= 1) lsum += __shfl_xor(lsum, m);
#pragma unroll
  for (int d = 0; d < 48; ++d) {
#pragma unroll
    for (int m = 1; m < 64; m <<= 1) o[d] += __shfl_xor(o[d], m);
  }
  if (lane == 0) {
    const float inv = 1.f / lsum;
    unsigned short* orow = o_out + (size_t)(b * kN + i) * kCT + h * kHD;
#pragma unroll
    for (int d4 = 0; d4 < 12; ++d4) {
      float4 g4 = *(const float4*)&qkvg[rowi + 3 * kCT + h * kHD + d4 * 4];
      uint32_t u0 = (uint32_t)f2bf(g4.x * o[d4 * 4 + 0] * inv) |
                    ((uint32_t)f2bf(g4.y * o[d4 * 4 + 1] * inv) << 16);
      uint32_t u1 = (uint32_t)f2bf(g4.z * o[d4 * 4 + 2] * inv) |
                    ((uint32_t)f2bf(g4.w * o[d4 * 4 + 3] * inv) << 16);
      *(uint32_t*)&orow[d4 * 4 + 0] = u0;
      *(uint32_t*)&orow[d4 * 4 + 2] = u1;
    }
  }
}

// ==========================================================================================
extern "C" void kernel_launch(void* const* d_in, const int* in_sizes, int n_in,
                              void* d_out, int out_size, void* d_ws, size_t ws_size,
                              hipStream_t stream) {
  const float* a      = (const float*)d_in[0];
  const float* s      = (const float*)d_in[1];
  const float* z      = (const float*)d_in[2];
  const float* mask   = (const float*)d_in[3];
  const float* Wg_ada = (const float*)d_in[4];
  const float* bg_ada = (const float*)d_in[5];
  const float* Wb_ada = (const float*)d_in[6];
  const float* Wq     = (const float*)d_in[7];
  const float* bq     = (const float*)d_in[8];
  const float* Wk     = (const float*)d_in[9];
  const float* Wv     = (const float*)d_in[10];
  const float* Wpb    = (const float*)d_in[11];
  const float* pn_g   = (const float*)d_in[12];
  const float* pn_b   = (const float*)d_in[13];
  const float* Wgate  = (const float*)d_in[14];
  const float* Wout   = (const float*)d_in[15];
  const float* Wog    = (const float*)d_in[16];
  const float* bog    = (const float*)d_in[17];
  float* out = (float*)d_out;

  char* p = (char*)d_ws;
  auto alloc = [&](size_t bytes) -> char* {
    char* r = p;
    p += (bytes + 255) & ~(size_t)255;
    return r;
  };
  float* a_ln  = (float*)alloc((size_t)1536 * 768 * 4);
  float* gb    = (float*)alloc((size_t)1536 * 1536 * 4);
  float* qkvg  = (float*)alloc((size_t)1536 * 3072 * 4);
  float* ogate = (float*)alloc((size_t)1536 * 768 * 4);
  unsigned short* s_ln   = (unsigned short*)alloc((size_t)1536 * 384 * 2);
  unsigned short* a_nrm  = (unsigned short*)alloc((size_t)1536 * 768 * 2);
  unsigned short* s_bf   = (unsigned short*)alloc((size_t)1536 * 384 * 2);
  unsigned short* o_g    = (unsigned short*)alloc((size_t)1536 * 768 * 2);
  unsigned short* pbias  = (unsigned short*)alloc((size_t)2 * 16 * 768 * 768 * 2);
  unsigned short* p_adaT = (unsigned short*)alloc((size_t)1536 * 384 * 2);
  unsigned short* p_qkvT = (unsigned short*)alloc((size_t)3072 * 768 * 2);
  unsigned short* WogT   = (unsigned short*)alloc((size_t)768 * 384 * 2);
  unsigned short* WoutT  = (unsigned short*)alloc((size_t)768 * 768 * 2);
  float* pb_ada = (float*)alloc(1536 * 4);
  float* pb_qk  = (float*)alloc(3072 * 4);
  float* gamW   = (float*)alloc(2048 * 4);
  float* pairC  = (float*)alloc(32 * 4);

  const int packTot = 1536 * 384 + 3072 * 768 + 768 * 384 + 768 * 768 + 1536 + 3072 +
                      1536 * 384 + 2048 + 32;
  pack_kernel<<<dim3((packTot + 255) / 256), 256, 0, stream>>>(
      Wg_ada, Wb_ada, bg_ada, bq, Wq, Wk, Wv, Wgate, Wog, Wout, s, Wpb, pn_g, pn_b,
      p_adaT, p_qkvT, WogT, WoutT, pb_ada, pb_qk, s_bf, gamW, pairC);
  ln_kernel<<<dim3(1536), 256, 0, stream>>>(a, a_ln, 768);
  ln_bf_kernel<<<dim3(1536), 256, 0, stream>>>(s, s_ln, 384);
  // gb = [ s_ln@Wg_ada + bg | s_ln@Wb_ada ]
  gemm_bf_kernel<<<dim3(12, 12), 256, 0, stream>>>(
      s_ln, p_adaT, pb_ada, nullptr, gb, 1536, 1536, 384, 1 << 30);
  anorm_kernel<<<dim3(1536 * 768 / 256), 256, 0, stream>>>(gb, a_ln, a_nrm);
  // qkvg = a_norm @ [Wq|Wk|Wv|Wgate] (+bq on q, sigmoid on gate cols)
  gemm_bf_kernel<<<dim3(24, 12), 256, 0, stream>>>(
      a_nrm, p_qkvT, pb_qk, nullptr, qkvg, 1536, 3072, 768, 2304);
  // ogate = sigmoid(s @ Wog + bog)
  gemm_bf_kernel<<<dim3(6, 12), 256, 0, stream>>>(
      s_bf, WogT, bog, nullptr, ogate, 1536, 768, 384, 0);
  pairbias2_kernel<<<dim3(3, 768, 2), 256, 0, stream>>>(z, mask, gamW, pairC, pbias);
  attn_kernel<<<dim3(192, 16, 2), 256, 0, stream>>>(qkvg, pbias, o_g);
  // out = ogate * (o_g @ Wout)
  gemm_bf_kernel<<<dim3(6, 12), 256, 0, stream>>>(
      o_g, WoutT, nullptr, ogate, out, 1536, 768, 768, 1 << 30);
}